// Round 11
// baseline (111.476 us; speedup 1.0000x reference)
//
#include <hip/hip_runtime.h>
#include <hip/hip_bf16.h>
#include <math.h>

// MultiBoxLoss: B=64, P=16800, G=32, C=2. 3-kernel pipeline:
// k_gt     : per-gt best-prior argmax (transposed) -> keys; packs gt table.
// k_match  : TRANSPOSED threshold phase: lane<->gt, gt data in VGPRs (loaded
//            once), 2 priors/iteration, one ballot per pair of priors ->
//            per-wave u64 threshold mask. Phase B: lane<->prior epilogue.
//            No dependent loads in the hot loop.
// k_select : 4-way bisection exact k-th largest; last block folds -> 3 scalars.

#define RCP(x) __builtin_amdgcn_rcpf(x)
typedef unsigned long long u64;

constexpr int GN = 32;
// per-batch gt pack (floats): [0]box x4*32 | [128]c035 x32 | [160]area x32
//                             | [192]lab x32 | [224]lm x320 | pad -> 576
constexpr int PACKF = 576;

__device__ __forceinline__ float sl1(float x) {
    float a = fabsf(x);
    return a < 1.f ? 0.5f * a * a : a - 0.5f;
}

// ---- k_gt: per-gt best prior (max iou, ties -> smallest p) + gt pack ----
constexpr int GPB = 4;
constexpr int GNT = 1024;
__global__ __launch_bounds__(GNT)
void k_gt(const float4* __restrict__ priors, const float* __restrict__ targets,
          u64* __restrict__ keys, float* __restrict__ pack,
          int* __restrict__ done, int P, int G) {
    const int b = blockIdx.y, g0 = blockIdx.x * GPB, tid = threadIdx.x;
    const int lane = tid & 63, w = tid >> 6;
    if (blockIdx.x == 0 && blockIdx.y == 0 && tid == 0) *done = 0;
    __shared__ float4 s_box[GPB];
    __shared__ float  s_at[GPB];
    __shared__ u64 s_wk[GNT / 64][GPB];
    if (tid < GPB) {
        const float* t = targets + ((size_t)b * G + g0 + tid) * 15;
        float4 v = make_float4(t[0], t[1], t[2], t[3]);
        float at = (v.z - v.x) * (v.w - v.y);
        s_box[tid] = v;
        s_at[tid] = at;
        float* pkw = pack + (size_t)b * PACKF;
        ((float4*)pkw)[g0 + tid] = v;
        pkw[128 + g0 + tid] = 0.35f * at;
        pkw[160 + g0 + tid] = at;
        pkw[192 + g0 + tid] = t[14];
    }
    {   // landmarks
        int q = tid - GPB;
        if (q >= 0 && q < GPB * 10) {
            int gg = g0 + q / 10, j = q % 10;
            pack[(size_t)b * PACKF + 224 + gg * 10 + j] =
                targets[((size_t)b * G + gg) * 15 + 4 + j];
        }
    }
    __syncthreads();
    float4 tb0 = s_box[0], tb1 = s_box[1], tb2 = s_box[2], tb3 = s_box[3];
    float at0 = s_at[0], at1 = s_at[1], at2 = s_at[2], at3 = s_at[3];

    float bv[GPB]; int bp[GPB];
    #pragma unroll
    for (int j = 0; j < GPB; ++j) { bv[j] = -1.f; bp[j] = 0; }

    for (int p = tid; p < P; p += GNT) {     // ascending p: '>' keeps smallest p
        float4 pr = priors[p];
        float hx = pr.z * 0.5f, hy = pr.w * 0.5f;
        float px0 = pr.x - hx, py0 = pr.y - hy;
        float px1 = pr.x + hx, py1 = pr.y + hy;
        float ap = (px1 - px0) * (py1 - py0);
        #pragma unroll
        for (int j = 0; j < GPB; ++j) {
            float4 tb = j == 0 ? tb0 : (j == 1 ? tb1 : (j == 2 ? tb2 : tb3));
            float at = j == 0 ? at0 : (j == 1 ? at1 : (j == 2 ? at2 : at3));
            float lx = fmaxf(tb.x, px0), ly = fmaxf(tb.y, py0);
            float rx = fminf(tb.z, px1), ry = fminf(tb.w, py1);
            float iw = fmaxf(rx - lx, 0.f), ih = fmaxf(ry - ly, 0.f);
            float inter = iw * ih;
            float iou = inter * RCP(at + ap - inter);
            if (iou > bv[j]) { bv[j] = iou; bp[j] = p; }
        }
    }
    #pragma unroll
    for (int j = 0; j < GPB; ++j) {
        u64 key = ((u64)__float_as_uint(bv[j]) << 32) | ~(unsigned)bp[j];
        #pragma unroll
        for (int o = 32; o > 0; o >>= 1) {
            u64 t = __shfl_down(key, o, 64);
            if (t > key) key = t;
        }
        if (lane == 0) s_wk[w][j] = key;
    }
    __syncthreads();
    if (tid < GPB) {
        u64 m = 0ull;
        #pragma unroll
        for (int q = 0; q < GNT / 64; ++q) { u64 t = s_wk[q][tid]; if (t > m) m = t; }
        keys[b * G + g0 + tid] = m;
    }
}

// ---- k_match: transposed ballot threshold + per-prior epilogue ----
__global__ __launch_bounds__(256)
void k_match(const float2* __restrict__ cls, const float4* __restrict__ loc,
             const float* __restrict__ lmd, const float4* __restrict__ priors,
             const float* __restrict__ pack, const u64* __restrict__ keys,
             float* __restrict__ bc, float* __restrict__ part, int P, int NB) {
    const int b = blockIdx.y, bx = blockIdx.x, tid = threadIdx.x;
    const int lane = tid & 63, w = tid >> 6;
    const float* __restrict__ pk = pack + (size_t)b * PACKF;
    const float4* __restrict__ gbox = (const float4*)pk;
    const float* __restrict__ garea = pk + 160;
    const float* __restrict__ glab = pk + 192;
    const float* __restrict__ glm  = pk + 224;

    __shared__ int s_fg[256];
    __shared__ int s_fv[256];
    __shared__ unsigned s_vm;
    __shared__ float s_red[4][8];

    s_fg[tid] = -1; s_fv[tid] = 0;
    __syncthreads();
    if (tid < GN) {                                   // forced-match scatter
        u64 key = keys[b * GN + tid];
        unsigned bp = ~(unsigned)key;
        bool val = __uint_as_float((unsigned)(key >> 32)) >= 0.2f;
        u64 bal = __ballot(val);
        if (tid == 0) s_vm = (unsigned)bal;
        int local = (int)bp - bx * 256;
        if (local >= 0 && local < 256) {
            atomicMax(&s_fg[local], tid);
            if (val) atomicOr(&s_fv[local], 1);
        }
    }

    int p = bx * 256 + tid;
    const bool act = p < P;
    // early cls load: latency hides under phase A
    float2 c = act ? cls[(size_t)b * P + p] : make_float2(0.f, 0.f);

    // ---- phase A (transposed): lane <-> gt; 2 priors per iteration ----
    const int gl = lane & 31, half = lane >> 5;
    float4 gtb = gbox[gl];                            // gt data in VGPRs, ONCE
    float gc = pk[128 + gl];                          // 0.35 * area_g
    const int pbase = bx * 256 + w * 64;
    u64 thrm = 0ull;
    #pragma unroll 8
    for (int i = 0; i < 32; ++i) {
        int p2 = pbase + 2 * i + half;
        bool a2 = p2 < P;
        float4 pr2 = a2 ? priors[p2] : make_float4(0.f, 0.f, 0.f, 0.f);
        float hx = pr2.z * 0.5f, hy = pr2.w * 0.5f;
        float qx0 = pr2.x - hx, qy0 = pr2.y - hy;
        float qx1 = pr2.x + hx, qy1 = pr2.y + hy;
        float ap35 = 0.35f * ((qx1 - qx0) * (qy1 - qy0));
        float lx = fmaxf(gtb.x, qx0), ly = fmaxf(gtb.y, qy0);
        float rx = fminf(gtb.z, qx1), ry = fminf(gtb.w, qy1);
        float iw = fmaxf(rx - lx, 0.f), ih = fmaxf(ry - ly, 0.f);
        bool pass = a2 && (fmaf(1.35f, iw * ih, -gc) >= ap35);
        u64 bal = __ballot(pass);                     // SGPR-uniform
        thrm |= (u64)((bal & 0xFFFFFFFFull) != 0ull) << (2 * i);
        thrm |= (u64)((bal >> 32) != 0ull) << (2 * i + 1);
    }
    __syncthreads();                                  // covers scatter
    const bool av = s_vm != 0u;

    // ---- phase B: lane <-> prior ----
    bool thr = act && ((thrm >> lane) & 1ull);
    int fidx = s_fg[tid];
    bool fv = s_fv[tid] != 0;
    bool pos = act && av && (fv || thr);

    float lse = 0.f, d = 0.f;
    if (act) {
        d = c.y - c.x;
        float m0 = fmaxf(d, 0.f);
        lse = m0 + __logf(__expf(-m0) + __expf(d - m0));   // logz - c.x >= 0
        bc[(size_t)b * P + p] = pos ? 0.f : lse;
    }

    float a_ll = 0.f, a_lm = 0.f, a_lcp = 0.f;
    bool posl = false;
    if (pos) {
        a_lcp = lse - d;                                   // logz - c.y
        float4 pr = priors[p];
        float hx = pr.z * 0.5f, hy = pr.w * 0.5f;
        float px0 = pr.x - hx, py0 = pr.y - hy;
        float px1 = pr.x + hx, py1 = pr.y + hy;
        float ap = (px1 - px0) * (py1 - py0);
        int bti2 = fidx;
        if (fidx < 0) {                                    // rare: full argmax
            float btv = -1.f;
            #pragma unroll 1
            for (int g = 0; g < GN; ++g) {
                float4 tb = gbox[g];
                float lx = fmaxf(tb.x, px0), ly = fmaxf(tb.y, py0);
                float rx = fminf(tb.z, px1), ry = fminf(tb.w, py1);
                float iw = fmaxf(rx - lx, 0.f), ih = fmaxf(ry - ly, 0.f);
                float inter = iw * ih;
                float iou = inter * RCP(garea[g] + ap - inter);
                if (iou > btv) { btv = iou; bti2 = g; }    // first-g argmax
            }
        }
        float4 tb = gbox[bti2];
        float rw = RCP(pr.z), rh = RCP(pr.w);
        float e0 = ((tb.x + tb.z) * 0.5f - pr.x) * rw * 10.f;
        float e1 = ((tb.y + tb.w) * 0.5f - pr.y) * rh * 10.f;
        float e2 = __logf((tb.z - tb.x) * rw) * 5.f;
        float e3 = __logf((tb.w - tb.y) * rh) * 5.f;
        float4 ld = loc[(size_t)b * P + p];
        a_ll = sl1(ld.x - e0) + sl1(ld.y - e1) + sl1(ld.z - e2) + sl1(ld.w - e3);
        if (glab[bti2] > 0.f) {                            // conf > 0
            posl = true;
            const float* lp = lmd + ((size_t)b * P + p) * 10;
            #pragma unroll
            for (int q = 0; q < 5; ++q) {
                float gx = (glm[bti2 * 10 + 2 * q]     - pr.x) * rw * 10.f;
                float gy = (glm[bti2 * 10 + 2 * q + 1] - pr.y) * rh * 10.f;
                a_lm += sl1(lp[2 * q] - gx) + sl1(lp[2 * q + 1] - gy);
            }
        }
    }

    u64 bpos = __ballot(pos);
    int npw  = __popcll(bpos);
    int np1w = __popcll(__ballot(posl));
    if (bpos) {                                   // skip shuffles for all-neg waves
        #pragma unroll
        for (int o = 32; o > 0; o >>= 1) {
            a_ll  += __shfl_down(a_ll,  o, 64);
            a_lm  += __shfl_down(a_lm,  o, 64);
            a_lcp += __shfl_down(a_lcp, o, 64);
        }
    }
    if (lane == 0) {
        s_red[w][0] = a_ll; s_red[w][1] = a_lm; s_red[w][2] = a_lcp;
        s_red[w][3] = (float)npw; s_red[w][4] = (float)np1w;
    }
    __syncthreads();
    if (tid == 0) {
        float* pp = part + ((size_t)b * NB + bx) * 8;
        #pragma unroll
        for (int j = 0; j < 5; ++j)
            pp[j] = s_red[0][j] + s_red[1][j] + s_red[2][j] + s_red[3][j];
    }
}

// ---- k_select: exact top-k via 4-way bisection; last block folds ----
constexpr int KNT = 1024;
constexpr int KNI = 17;      // ceil(16800 / 1024)
__global__ __launch_bounds__(KNT)
void k_select(const float* __restrict__ bc, const float* __restrict__ part,
              float* __restrict__ part2, float* __restrict__ out,
              int* __restrict__ done, int P, int NB, int B) {
    const int b = blockIdx.x, tid = threadIdx.x;
    const int lane = tid & 63, w = tid >> 6;
    __shared__ float s_r[5];
    __shared__ u64   s_cw[16];
    __shared__ u64   s_ct;
    __shared__ float s_rf[16][2];
    __shared__ float s_ts2[2];
    __shared__ int   s_last;

    unsigned ul[KNI];
    #pragma unroll
    for (int i = 0; i < KNI; ++i) {
        int idx = i * KNT + tid;
        ul[i] = idx < P ? __float_as_uint(bc[(size_t)b * P + idx]) : 0u;
    }
    if (w < 5) {                                  // wave j reduces part field j
        float s = 0.f;
        for (int bx = lane; bx < NB; bx += 64) s += part[((size_t)b * NB + bx) * 8 + w];
        #pragma unroll
        for (int o = 32; o > 0; o >>= 1) s += __shfl_down(s, o, 64);
        if (lane == 0) s_r[w] = s;
    }
    __syncthreads();
    const float t_ll = s_r[0], t_lm = s_r[1], t_lcp = s_r[2];
    const float t_np = s_r[3], t_np1 = s_r[4];
    int k = (int)(t_np + 0.5f) * 7;
    if (k > P - 1) k = P - 1;

    float topk = 0.f;
    if (k > 0) {
        unsigned lo = 0u, hi = 0x7f800000u;       // finite non-negative values
        while (lo < hi) {                          // ~15 rounds (4-way)
            unsigned span = hi - lo;
            unsigned m1 = lo + ((span + 3) >> 2);
            unsigned m2 = lo + ((span + 1) >> 1);
            unsigned m3 = hi - (span >> 2);
            int c1 = 0, c2 = 0, c3 = 0;
            #pragma unroll
            for (int i = 0; i < KNI; ++i) {
                unsigned u = ul[i];
                c1 += u >= m1 ? 1 : 0;
                c2 += u >= m2 ? 1 : 0;
                c3 += u >= m3 ? 1 : 0;
            }
            u64 pkk = (u64)c1 | ((u64)c2 << 20) | ((u64)c3 << 40);
            #pragma unroll
            for (int o = 32; o > 0; o >>= 1) pkk += __shfl_down(pkk, o, 64);
            if (lane == 0) s_cw[w] = pkk;
            __syncthreads();
            if (w == 0) {                          // wave-0 shuffle fold
                u64 t = (lane < 16) ? s_cw[lane] : 0ull;
                #pragma unroll
                for (int o = 8; o > 0; o >>= 1) t += __shfl_down(t, o, 64);
                if (lane == 0) s_ct = t;
            }
            __syncthreads();
            u64 t = s_ct;
            int C1 = (int)(t & 0xFFFFFu);
            int C2 = (int)((t >> 20) & 0xFFFFFu);
            int C3 = (int)((t >> 40) & 0xFFFFFu);
            if      (C3 >= k) lo = m3;
            else if (C2 >= k) { lo = m2; hi = m3 - 1; }
            else if (C1 >= k) { lo = m1; hi = m2 - 1; }
            else hi = m1 - 1;
        }
        float fT = __uint_as_float(lo);            // exact k-th largest
        float s = 0.f, cf = 0.f;
        #pragma unroll
        for (int i = 0; i < KNI; ++i)
            if (ul[i] > lo) { s += __uint_as_float(ul[i]); cf += 1.f; }
        #pragma unroll
        for (int o = 32; o > 0; o >>= 1) {
            s  += __shfl_down(s, o, 64);
            cf += __shfl_down(cf, o, 64);
        }
        if (lane == 0) { s_rf[w][0] = s; s_rf[w][1] = cf; }
        __syncthreads();
        if (w == 0) {
            float a = (lane < 16) ? s_rf[lane][0] : 0.f;
            float bb = (lane < 16) ? s_rf[lane][1] : 0.f;
            #pragma unroll
            for (int o = 8; o > 0; o >>= 1) {
                a  += __shfl_down(a, o, 64);
                bb += __shfl_down(bb, o, 64);
            }
            if (lane == 0) { s_ts2[0] = a; s_ts2[1] = bb; }
        }
        __syncthreads();
        topk = s_ts2[0] + ((float)k - s_ts2[1]) * fT;  // ties add (k-cnt)*T
    }
    if (tid == 0) {
        float* pp = part2 + b * 8;
        pp[0] = t_ll; pp[1] = t_lm; pp[2] = t_lcp;
        pp[3] = topk; pp[4] = t_np; pp[5] = t_np1;
        __threadfence();
        int old = atomicAdd(done, 1);
        s_last = (old == B - 1) ? 1 : 0;
    }
    __syncthreads();
    if (s_last && w == 0) {                        // last block folds all rows
        __threadfence();
        volatile float* vp = part2;
        float ll = 0.f, lm = 0.f, lc = 0.f, tk = 0.f, np = 0.f, np1 = 0.f;
        for (int bb = lane; bb < B; bb += 64) {
            ll  += vp[bb * 8 + 0];
            lm  += vp[bb * 8 + 1];
            lc  += vp[bb * 8 + 2];
            tk  += vp[bb * 8 + 3];
            np  += vp[bb * 8 + 4];
            np1 += vp[bb * 8 + 5];
        }
        #pragma unroll
        for (int o = 32; o > 0; o >>= 1) {
            ll  += __shfl_down(ll,  o, 64);
            lm  += __shfl_down(lm,  o, 64);
            lc  += __shfl_down(lc,  o, 64);
            tk  += __shfl_down(tk,  o, 64);
            np  += __shfl_down(np,  o, 64);
            np1 += __shfl_down(np1, o, 64);
        }
        if (lane == 0) {
            float N = fmaxf(np, 1.f), N1 = fmaxf(np1, 1.f);
            out[0] = ll / N;
            out[1] = (lc + tk) / N;
            out[2] = lm / N1;
        }
    }
}

extern "C" void kernel_launch(void* const* d_in, const int* in_sizes, int n_in,
                              void* d_out, int out_size, void* d_ws, size_t ws_size,
                              hipStream_t stream) {
    const float2* cls    = (const float2*)d_in[0];
    const float4* loc    = (const float4*)d_in[1];
    const float* lmd     = (const float*)d_in[2];
    const float4* priors = (const float4*)d_in[3];
    const float* targets = (const float*)d_in[4];
    int P = in_sizes[3] / 4;            // 16800
    int B = (in_sizes[1] / 4) / P;      // 64
    int G = in_sizes[4] / (15 * B);     // 32
    int NB = (P + 255) / 256;           // 66

    size_t off = 0;
    u64* keys    = (u64*)d_ws;                     off += (size_t)B * G * 8;
    float* pack  = (float*)((char*)d_ws + off);    off += (size_t)B * PACKF * 4;
    float* part  = (float*)((char*)d_ws + off);    off += (size_t)B * NB * 8 * 4;
    float* part2 = (float*)((char*)d_ws + off);    off += (size_t)B * 8 * 4;
    int* done    = (int*)((char*)d_ws + off);      off += 256;
    off = (off + 255) & ~(size_t)255;
    float* bc    = (float*)((char*)d_ws + off);

    dim3 ggt((G + GPB - 1) / GPB, B);
    k_gt<<<ggt, GNT, 0, stream>>>(priors, targets, keys, pack, done, P, G);
    dim3 gm(NB, B);
    k_match<<<gm, 256, 0, stream>>>(cls, loc, lmd, priors, pack, keys, bc, part, P, NB);
    k_select<<<B, KNT, 0, stream>>>(bc, part, part2, (float*)d_out, done, P, NB, B);
}

// Round 12
// 107.530 us; speedup vs baseline: 1.0367x; 1.0367x over previous
//
#include <hip/hip_runtime.h>
#include <hip/hip_bf16.h>
#include <math.h>

// ABLATION ROUND: partition k_match's invariant ~43us with per-dispatch timings.
// Dispatch order: k_gt -> kprobe_stream -> kprobe_ng -> kmatch_v0 -> k_select.
// Probes write the same bc/part buffers that kmatch_v0 fully rewrites afterward,
// so results are identical to round 10's kernel.

#define RCP(x) __builtin_amdgcn_rcpf(x)
typedef unsigned long long u64;

constexpr int GN = 32;
constexpr int PACKF = 576;

__device__ __forceinline__ float sl1(float x) {
    float a = fabsf(x);
    return a < 1.f ? 0.5f * a * a : a - 0.5f;
}

// ---- k_gt: per-gt best prior (max iou, ties -> smallest p) + gt pack ----
constexpr int GPB = 4;
constexpr int GNT = 1024;
__global__ __launch_bounds__(GNT)
void k_gt(const float4* __restrict__ priors, const float* __restrict__ targets,
          u64* __restrict__ keys, float* __restrict__ pack,
          int* __restrict__ done, int P, int G) {
    const int b = blockIdx.y, g0 = blockIdx.x * GPB, tid = threadIdx.x;
    const int lane = tid & 63, w = tid >> 6;
    if (blockIdx.x == 0 && blockIdx.y == 0 && tid == 0) *done = 0;
    __shared__ float4 s_box[GPB];
    __shared__ float  s_at[GPB];
    __shared__ u64 s_wk[GNT / 64][GPB];
    if (tid < GPB) {
        const float* t = targets + ((size_t)b * G + g0 + tid) * 15;
        float4 v = make_float4(t[0], t[1], t[2], t[3]);
        float at = (v.z - v.x) * (v.w - v.y);
        s_box[tid] = v;
        s_at[tid] = at;
        float* pkw = pack + (size_t)b * PACKF;
        ((float4*)pkw)[g0 + tid] = v;
        pkw[128 + g0 + tid] = 0.35f * at;
        pkw[160 + g0 + tid] = at;
        pkw[192 + g0 + tid] = t[14];
    }
    {
        int q = tid - GPB;
        if (q >= 0 && q < GPB * 10) {
            int gg = g0 + q / 10, j = q % 10;
            pack[(size_t)b * PACKF + 224 + gg * 10 + j] =
                targets[((size_t)b * G + gg) * 15 + 4 + j];
        }
    }
    __syncthreads();
    float4 tb0 = s_box[0], tb1 = s_box[1], tb2 = s_box[2], tb3 = s_box[3];
    float at0 = s_at[0], at1 = s_at[1], at2 = s_at[2], at3 = s_at[3];

    float bv[GPB]; int bp[GPB];
    #pragma unroll
    for (int j = 0; j < GPB; ++j) { bv[j] = -1.f; bp[j] = 0; }

    for (int p = tid; p < P; p += GNT) {
        float4 pr = priors[p];
        float hx = pr.z * 0.5f, hy = pr.w * 0.5f;
        float px0 = pr.x - hx, py0 = pr.y - hy;
        float px1 = pr.x + hx, py1 = pr.y + hy;
        float ap = (px1 - px0) * (py1 - py0);
        #pragma unroll
        for (int j = 0; j < GPB; ++j) {
            float4 tb = j == 0 ? tb0 : (j == 1 ? tb1 : (j == 2 ? tb2 : tb3));
            float at = j == 0 ? at0 : (j == 1 ? at1 : (j == 2 ? at2 : at3));
            float lx = fmaxf(tb.x, px0), ly = fmaxf(tb.y, py0);
            float rx = fminf(tb.z, px1), ry = fminf(tb.w, py1);
            float iw = fmaxf(rx - lx, 0.f), ih = fmaxf(ry - ly, 0.f);
            float inter = iw * ih;
            float iou = inter * RCP(at + ap - inter);
            if (iou > bv[j]) { bv[j] = iou; bp[j] = p; }
        }
    }
    #pragma unroll
    for (int j = 0; j < GPB; ++j) {
        u64 key = ((u64)__float_as_uint(bv[j]) << 32) | ~(unsigned)bp[j];
        #pragma unroll
        for (int o = 32; o > 0; o >>= 1) {
            u64 t = __shfl_down(key, o, 64);
            if (t > key) key = t;
        }
        if (lane == 0) s_wk[w][j] = key;
    }
    __syncthreads();
    if (tid < GPB) {
        u64 m = 0ull;
        #pragma unroll
        for (int q = 0; q < GNT / 64; ++q) { u64 t = s_wk[q][tid]; if (t > m) m = t; }
        keys[b * G + g0 + tid] = m;
    }
}

// ---- PROBE 1: pure stream floor (same grid as k_match) ----
__global__ __launch_bounds__(256)
void kprobe_stream(const float2* __restrict__ cls, float* __restrict__ bc, int P) {
    const int b = blockIdx.y, bx = blockIdx.x, tid = threadIdx.x;
    int p = bx * 256 + tid;
    if (p < P) {
        float2 c = cls[(size_t)b * P + p];
        bc[(size_t)b * P + p] = c.x + c.y;
    }
}

// ---- PROBE 2: full k_match minus the 32-gt loop (g=0 only) ----
__global__ __launch_bounds__(256)
void kprobe_ng(const float2* __restrict__ cls, const float4* __restrict__ loc,
               const float* __restrict__ lmd, const float4* __restrict__ priors,
               const float* __restrict__ pack, const u64* __restrict__ keys,
               float* __restrict__ bc, float* __restrict__ part, int P, int NB) {
    const int b = blockIdx.y, bx = blockIdx.x, tid = threadIdx.x;
    const int lane = tid & 63, w = tid >> 6;
    const float* __restrict__ pk = pack + (size_t)b * PACKF;
    const float4* __restrict__ gbox = (const float4*)pk;
    const float* __restrict__ gc35 = pk + 128;
    const float* __restrict__ garea = pk + 160;
    const float* __restrict__ glab = pk + 192;
    const float* __restrict__ glm  = pk + 224;

    __shared__ int s_fg[256];
    __shared__ int s_fv[256];
    __shared__ unsigned s_vm;
    __shared__ float s_red[4][8];

    s_fg[tid] = -1; s_fv[tid] = 0;
    __syncthreads();
    if (tid < GN) {
        u64 key = keys[b * GN + tid];
        unsigned bp = ~(unsigned)key;
        bool val = __uint_as_float((unsigned)(key >> 32)) >= 0.2f;
        u64 bal = __ballot(val);
        if (tid == 0) s_vm = (unsigned)bal;
        int local = (int)bp - bx * 256;
        if (local >= 0 && local < 256) {
            atomicMax(&s_fg[local], tid);
            if (val) atomicOr(&s_fv[local], 1);
        }
    }
    __syncthreads();
    const bool av = s_vm != 0u;

    int p = bx * 256 + tid;
    const bool act = p < P;
    float2 c = act ? cls[(size_t)b * P + p] : make_float2(0.f, 0.f);
    float4 pr = act ? priors[p] : make_float4(0.f, 0.f, 0.f, 0.f);
    float hx = pr.z * 0.5f, hy = pr.w * 0.5f;
    float px0 = pr.x - hx, py0 = pr.y - hy;
    float px1 = pr.x + hx, py1 = pr.y + hy;
    float ap = (px1 - px0) * (py1 - py0);
    float ap35 = 0.35f * ap;

    // g = 0 ONLY (ablated loop)
    float qmax = -INFINITY;
    {
        float4 tb = gbox[0];
        float lx = fmaxf(tb.x, px0), ly = fmaxf(tb.y, py0);
        float rx = fminf(tb.z, px1), ry = fminf(tb.w, py1);
        float iw = fmaxf(rx - lx, 0.f), ih = fmaxf(ry - ly, 0.f);
        qmax = fmaxf(qmax, fmaf(1.35f, iw * ih, -gc35[0]));
    }
    bool thr = act && (qmax >= ap35);
    int fidx = s_fg[tid];
    bool fv = s_fv[tid] != 0;
    bool pos = act && av && (fv || thr);

    float lse = 0.f, d = 0.f;
    if (act) {
        d = c.y - c.x;
        float m0 = fmaxf(d, 0.f);
        lse = m0 + __logf(__expf(-m0) + __expf(d - m0));
        bc[(size_t)b * P + p] = pos ? 0.f : lse;
    }

    float a_ll = 0.f, a_lm = 0.f, a_lcp = 0.f;
    bool posl = false;
    if (pos) {
        a_lcp = lse - d;
        int bti2 = fidx < 0 ? 0 : fidx;
        float4 tb = gbox[bti2];
        float rw = RCP(pr.z), rh = RCP(pr.w);
        float e0 = ((tb.x + tb.z) * 0.5f - pr.x) * rw * 10.f;
        float e1 = ((tb.y + tb.w) * 0.5f - pr.y) * rh * 10.f;
        float e2 = __logf((tb.z - tb.x) * rw) * 5.f;
        float e3 = __logf((tb.w - tb.y) * rh) * 5.f;
        float4 ld = loc[(size_t)b * P + p];
        a_ll = sl1(ld.x - e0) + sl1(ld.y - e1) + sl1(ld.z - e2) + sl1(ld.w - e3);
        if (glab[bti2] > 0.f) {
            posl = true;
            const float* lp = lmd + ((size_t)b * P + p) * 10;
            #pragma unroll
            for (int q = 0; q < 5; ++q) {
                float gx = (glm[bti2 * 10 + 2 * q]     - pr.x) * rw * 10.f;
                float gy = (glm[bti2 * 10 + 2 * q + 1] - pr.y) * rh * 10.f;
                a_lm += sl1(lp[2 * q] - gx) + sl1(lp[2 * q + 1] - gy);
            }
        }
    }

    u64 bpos = __ballot(pos);
    int npw  = __popcll(bpos);
    int np1w = __popcll(__ballot(posl));
    if (bpos) {
        #pragma unroll
        for (int o = 32; o > 0; o >>= 1) {
            a_ll  += __shfl_down(a_ll,  o, 64);
            a_lm  += __shfl_down(a_lm,  o, 64);
            a_lcp += __shfl_down(a_lcp, o, 64);
        }
    }
    if (lane == 0) {
        s_red[w][0] = a_ll; s_red[w][1] = a_lm; s_red[w][2] = a_lcp;
        s_red[w][3] = (float)npw; s_red[w][4] = (float)np1w;
    }
    __syncthreads();
    if (tid == 0) {
        float* pp = part + ((size_t)b * NB + bx) * 8;
        #pragma unroll
        for (int j = 0; j < 5; ++j)
            pp[j] = s_red[0][j] + s_red[1][j] + s_red[2][j] + s_red[3][j];
    }
}

// ---- kmatch_v0: unchanged round-10 kernel (the real one) ----
__global__ __launch_bounds__(256)
void kmatch_v0(const float2* __restrict__ cls, const float4* __restrict__ loc,
               const float* __restrict__ lmd, const float4* __restrict__ priors,
               const float* __restrict__ pack, const u64* __restrict__ keys,
               float* __restrict__ bc, float* __restrict__ part, int P, int NB) {
    const int b = blockIdx.y, bx = blockIdx.x, tid = threadIdx.x;
    const int lane = tid & 63, w = tid >> 6;
    const float* __restrict__ pk = pack + (size_t)b * PACKF;
    const float4* __restrict__ gbox = (const float4*)pk;
    const float* __restrict__ gc35 = pk + 128;
    const float* __restrict__ garea = pk + 160;
    const float* __restrict__ glab = pk + 192;
    const float* __restrict__ glm  = pk + 224;

    __shared__ int s_fg[256];
    __shared__ int s_fv[256];
    __shared__ unsigned s_vm;
    __shared__ float s_red[4][8];

    s_fg[tid] = -1; s_fv[tid] = 0;
    __syncthreads();
    if (tid < GN) {
        u64 key = keys[b * GN + tid];
        unsigned bp = ~(unsigned)key;
        bool val = __uint_as_float((unsigned)(key >> 32)) >= 0.2f;
        u64 bal = __ballot(val);
        if (tid == 0) s_vm = (unsigned)bal;
        int local = (int)bp - bx * 256;
        if (local >= 0 && local < 256) {
            atomicMax(&s_fg[local], tid);
            if (val) atomicOr(&s_fv[local], 1);
        }
    }
    __syncthreads();
    const bool av = s_vm != 0u;

    int p = bx * 256 + tid;
    const bool act = p < P;
    float2 c = act ? cls[(size_t)b * P + p] : make_float2(0.f, 0.f);
    float4 pr = act ? priors[p] : make_float4(0.f, 0.f, 0.f, 0.f);
    float hx = pr.z * 0.5f, hy = pr.w * 0.5f;
    float px0 = pr.x - hx, py0 = pr.y - hy;
    float px1 = pr.x + hx, py1 = pr.y + hy;
    float ap = (px1 - px0) * (py1 - py0);
    float ap35 = 0.35f * ap;

    float qmax = -INFINITY;
    #pragma unroll
    for (int g = 0; g < GN; ++g) {
        float4 tb = gbox[g];
        float lx = fmaxf(tb.x, px0), ly = fmaxf(tb.y, py0);
        float rx = fminf(tb.z, px1), ry = fminf(tb.w, py1);
        float iw = fmaxf(rx - lx, 0.f), ih = fmaxf(ry - ly, 0.f);
        qmax = fmaxf(qmax, fmaf(1.35f, iw * ih, -gc35[g]));
    }
    bool thr = act && (qmax >= ap35);
    int fidx = s_fg[tid];
    bool fv = s_fv[tid] != 0;
    bool pos = act && av && (fv || thr);

    float lse = 0.f, d = 0.f;
    if (act) {
        d = c.y - c.x;
        float m0 = fmaxf(d, 0.f);
        lse = m0 + __logf(__expf(-m0) + __expf(d - m0));
        bc[(size_t)b * P + p] = pos ? 0.f : lse;
    }

    float a_ll = 0.f, a_lm = 0.f, a_lcp = 0.f;
    bool posl = false;
    if (pos) {
        a_lcp = lse - d;
        int bti2 = fidx;
        if (fidx < 0) {
            float btv = -1.f;
            #pragma unroll 1
            for (int g = 0; g < GN; ++g) {
                float4 tb = gbox[g];
                float lx = fmaxf(tb.x, px0), ly = fmaxf(tb.y, py0);
                float rx = fminf(tb.z, px1), ry = fminf(tb.w, py1);
                float iw = fmaxf(rx - lx, 0.f), ih = fmaxf(ry - ly, 0.f);
                float inter = iw * ih;
                float iou = inter * RCP(garea[g] + ap - inter);
                if (iou > btv) { btv = iou; bti2 = g; }
            }
        }
        float4 tb = gbox[bti2];
        float rw = RCP(pr.z), rh = RCP(pr.w);
        float e0 = ((tb.x + tb.z) * 0.5f - pr.x) * rw * 10.f;
        float e1 = ((tb.y + tb.w) * 0.5f - pr.y) * rh * 10.f;
        float e2 = __logf((tb.z - tb.x) * rw) * 5.f;
        float e3 = __logf((tb.w - tb.y) * rh) * 5.f;
        float4 ld = loc[(size_t)b * P + p];
        a_ll = sl1(ld.x - e0) + sl1(ld.y - e1) + sl1(ld.z - e2) + sl1(ld.w - e3);
        if (glab[bti2] > 0.f) {
            posl = true;
            const float* lp = lmd + ((size_t)b * P + p) * 10;
            #pragma unroll
            for (int q = 0; q < 5; ++q) {
                float gx = (glm[bti2 * 10 + 2 * q]     - pr.x) * rw * 10.f;
                float gy = (glm[bti2 * 10 + 2 * q + 1] - pr.y) * rh * 10.f;
                a_lm += sl1(lp[2 * q] - gx) + sl1(lp[2 * q + 1] - gy);
            }
        }
    }

    u64 bpos = __ballot(pos);
    int npw  = __popcll(bpos);
    int np1w = __popcll(__ballot(posl));
    if (bpos) {
        #pragma unroll
        for (int o = 32; o > 0; o >>= 1) {
            a_ll  += __shfl_down(a_ll,  o, 64);
            a_lm  += __shfl_down(a_lm,  o, 64);
            a_lcp += __shfl_down(a_lcp, o, 64);
        }
    }
    if (lane == 0) {
        s_red[w][0] = a_ll; s_red[w][1] = a_lm; s_red[w][2] = a_lcp;
        s_red[w][3] = (float)npw; s_red[w][4] = (float)np1w;
    }
    __syncthreads();
    if (tid == 0) {
        float* pp = part + ((size_t)b * NB + bx) * 8;
        #pragma unroll
        for (int j = 0; j < 5; ++j)
            pp[j] = s_red[0][j] + s_red[1][j] + s_red[2][j] + s_red[3][j];
    }
}

// ---- k_select: exact top-k via 4-way bisection; last block folds ----
constexpr int KNT = 1024;
constexpr int KNI = 17;
__global__ __launch_bounds__(KNT)
void k_select(const float* __restrict__ bc, const float* __restrict__ part,
              float* __restrict__ part2, float* __restrict__ out,
              int* __restrict__ done, int P, int NB, int B) {
    const int b = blockIdx.x, tid = threadIdx.x;
    const int lane = tid & 63, w = tid >> 6;
    __shared__ float s_r[5];
    __shared__ u64   s_cw[16];
    __shared__ u64   s_ct;
    __shared__ float s_rf[16][2];
    __shared__ float s_ts2[2];
    __shared__ int   s_last;

    unsigned ul[KNI];
    #pragma unroll
    for (int i = 0; i < KNI; ++i) {
        int idx = i * KNT + tid;
        ul[i] = idx < P ? __float_as_uint(bc[(size_t)b * P + idx]) : 0u;
    }
    if (w < 5) {
        float s = 0.f;
        for (int bx = lane; bx < NB; bx += 64) s += part[((size_t)b * NB + bx) * 8 + w];
        #pragma unroll
        for (int o = 32; o > 0; o >>= 1) s += __shfl_down(s, o, 64);
        if (lane == 0) s_r[w] = s;
    }
    __syncthreads();
    const float t_ll = s_r[0], t_lm = s_r[1], t_lcp = s_r[2];
    const float t_np = s_r[3], t_np1 = s_r[4];
    int k = (int)(t_np + 0.5f) * 7;
    if (k > P - 1) k = P - 1;

    float topk = 0.f;
    if (k > 0) {
        unsigned lo = 0u, hi = 0x7f800000u;
        while (lo < hi) {
            unsigned span = hi - lo;
            unsigned m1 = lo + ((span + 3) >> 2);
            unsigned m2 = lo + ((span + 1) >> 1);
            unsigned m3 = hi - (span >> 2);
            int c1 = 0, c2 = 0, c3 = 0;
            #pragma unroll
            for (int i = 0; i < KNI; ++i) {
                unsigned u = ul[i];
                c1 += u >= m1 ? 1 : 0;
                c2 += u >= m2 ? 1 : 0;
                c3 += u >= m3 ? 1 : 0;
            }
            u64 pkk = (u64)c1 | ((u64)c2 << 20) | ((u64)c3 << 40);
            #pragma unroll
            for (int o = 32; o > 0; o >>= 1) pkk += __shfl_down(pkk, o, 64);
            if (lane == 0) s_cw[w] = pkk;
            __syncthreads();
            if (w == 0) {
                u64 t = (lane < 16) ? s_cw[lane] : 0ull;
                #pragma unroll
                for (int o = 8; o > 0; o >>= 1) t += __shfl_down(t, o, 64);
                if (lane == 0) s_ct = t;
            }
            __syncthreads();
            u64 t = s_ct;
            int C1 = (int)(t & 0xFFFFFu);
            int C2 = (int)((t >> 20) & 0xFFFFFu);
            int C3 = (int)((t >> 40) & 0xFFFFFu);
            if      (C3 >= k) lo = m3;
            else if (C2 >= k) { lo = m2; hi = m3 - 1; }
            else if (C1 >= k) { lo = m1; hi = m2 - 1; }
            else hi = m1 - 1;
        }
        float fT = __uint_as_float(lo);
        float s = 0.f, cf = 0.f;
        #pragma unroll
        for (int i = 0; i < KNI; ++i)
            if (ul[i] > lo) { s += __uint_as_float(ul[i]); cf += 1.f; }
        #pragma unroll
        for (int o = 32; o > 0; o >>= 1) {
            s  += __shfl_down(s, o, 64);
            cf += __shfl_down(cf, o, 64);
        }
        if (lane == 0) { s_rf[w][0] = s; s_rf[w][1] = cf; }
        __syncthreads();
        if (w == 0) {
            float a = (lane < 16) ? s_rf[lane][0] : 0.f;
            float bb = (lane < 16) ? s_rf[lane][1] : 0.f;
            #pragma unroll
            for (int o = 8; o > 0; o >>= 1) {
                a  += __shfl_down(a, o, 64);
                bb += __shfl_down(bb, o, 64);
            }
            if (lane == 0) { s_ts2[0] = a; s_ts2[1] = bb; }
        }
        __syncthreads();
        topk = s_ts2[0] + ((float)k - s_ts2[1]) * fT;
    }
    if (tid == 0) {
        float* pp = part2 + b * 8;
        pp[0] = t_ll; pp[1] = t_lm; pp[2] = t_lcp;
        pp[3] = topk; pp[4] = t_np; pp[5] = t_np1;
        __threadfence();
        int old = atomicAdd(done, 1);
        s_last = (old == B - 1) ? 1 : 0;
    }
    __syncthreads();
    if (s_last && w == 0) {
        __threadfence();
        volatile float* vp = part2;
        float ll = 0.f, lm = 0.f, lc = 0.f, tk = 0.f, np = 0.f, np1 = 0.f;
        for (int bb = lane; bb < B; bb += 64) {
            ll  += vp[bb * 8 + 0];
            lm  += vp[bb * 8 + 1];
            lc  += vp[bb * 8 + 2];
            tk  += vp[bb * 8 + 3];
            np  += vp[bb * 8 + 4];
            np1 += vp[bb * 8 + 5];
        }
        #pragma unroll
        for (int o = 32; o > 0; o >>= 1) {
            ll  += __shfl_down(ll,  o, 64);
            lm  += __shfl_down(lm,  o, 64);
            lc  += __shfl_down(lc,  o, 64);
            tk  += __shfl_down(tk,  o, 64);
            np  += __shfl_down(np,  o, 64);
            np1 += __shfl_down(np1, o, 64);
        }
        if (lane == 0) {
            float N = fmaxf(np, 1.f), N1 = fmaxf(np1, 1.f);
            out[0] = ll / N;
            out[1] = (lc + tk) / N;
            out[2] = lm / N1;
        }
    }
}

extern "C" void kernel_launch(void* const* d_in, const int* in_sizes, int n_in,
                              void* d_out, int out_size, void* d_ws, size_t ws_size,
                              hipStream_t stream) {
    const float2* cls    = (const float2*)d_in[0];
    const float4* loc    = (const float4*)d_in[1];
    const float* lmd     = (const float*)d_in[2];
    const float4* priors = (const float4*)d_in[3];
    const float* targets = (const float*)d_in[4];
    int P = in_sizes[3] / 4;            // 16800
    int B = (in_sizes[1] / 4) / P;      // 64
    int G = in_sizes[4] / (15 * B);     // 32
    int NB = (P + 255) / 256;           // 66

    size_t off = 0;
    u64* keys    = (u64*)d_ws;                     off += (size_t)B * G * 8;
    float* pack  = (float*)((char*)d_ws + off);    off += (size_t)B * PACKF * 4;
    float* part  = (float*)((char*)d_ws + off);    off += (size_t)B * NB * 8 * 4;
    float* part2 = (float*)((char*)d_ws + off);    off += (size_t)B * 8 * 4;
    int* done    = (int*)((char*)d_ws + off);      off += 256;
    off = (off + 255) & ~(size_t)255;
    float* bc    = (float*)((char*)d_ws + off);

    dim3 ggt((G + GPB - 1) / GPB, B);
    k_gt<<<ggt, GNT, 0, stream>>>(priors, targets, keys, pack, done, P, G);
    dim3 gm(NB, B);
    // probes (scratch into bc/part, fully overwritten by kmatch_v0 next)
    kprobe_stream<<<gm, 256, 0, stream>>>(cls, bc, P);
    kprobe_ng<<<gm, 256, 0, stream>>>(cls, loc, lmd, priors, pack, keys, bc, part, P, NB);
    // the real kernel
    kmatch_v0<<<gm, 256, 0, stream>>>(cls, loc, lmd, priors, pack, keys, bc, part, P, NB);
    k_select<<<B, KNT, 0, stream>>>(bc, part, part2, (float*)d_out, done, P, NB, B);
}

// Round 13
// 89.004 us; speedup vs baseline: 1.2525x; 1.2081x over previous
//
#include <hip/hip_runtime.h>
#include <hip/hip_bf16.h>
#include <math.h>

// MultiBoxLoss: B=64, P=16800, G=32, C=2. 3-kernel pipeline:
// k_gt     : per-gt best-prior argmax AND per-prior threshold bitmask
//            (ballot per 64 priors) -> keys + wmask; packs gt table.
// k_match  : threshold = 8 uniform u64 loads + OR (g-loop DELETED, proven
//            ~33us by r12 ablation); forced-match via LDS scatter; rare
//            positives full argmax; writes bc + 5 block partials.
// k_select : 4-way bisection exact k-th largest; last block folds -> 3 scalars.

#define RCP(x) __builtin_amdgcn_rcpf(x)
typedef unsigned long long u64;

constexpr int GN = 32;
constexpr int PACKF = 576;
constexpr int NW64A = 264;   // allocated mask words per (batch, chunk); 263 used

__device__ __forceinline__ float sl1(float x) {
    float a = fabsf(x);
    return a < 1.f ? 0.5f * a * a : a - 0.5f;
}

// ---- k_gt: argmax + threshold bitmask + gt pack ----
constexpr int GPB = 4;       // gts per block (chunk)
constexpr int GNT = 1024;
__global__ __launch_bounds__(GNT)
void k_gt(const float4* __restrict__ priors, const float* __restrict__ targets,
          u64* __restrict__ keys, float* __restrict__ pack, u64* __restrict__ wmask,
          int* __restrict__ done, int P, int G, int NCH) {
    const int b = blockIdx.y, cx = blockIdx.x, g0 = cx * GPB, tid = threadIdx.x;
    const int lane = tid & 63, w = tid >> 6;
    if (cx == 0 && b == 0 && tid == 0) *done = 0;
    __shared__ float4 s_box[GPB];
    __shared__ float  s_at[GPB];
    __shared__ u64 s_wk[GNT / 64][GPB];
    if (tid < GPB) {
        const float* t = targets + ((size_t)b * G + g0 + tid) * 15;
        float4 v = make_float4(t[0], t[1], t[2], t[3]);
        float at = (v.z - v.x) * (v.w - v.y);
        s_box[tid] = v;
        s_at[tid] = at;
        float* pkw = pack + (size_t)b * PACKF;
        ((float4*)pkw)[g0 + tid] = v;
        pkw[128 + g0 + tid] = 0.35f * at;
        pkw[160 + g0 + tid] = at;
        pkw[192 + g0 + tid] = t[14];
    }
    {
        int q = tid - GPB;
        if (q >= 0 && q < GPB * 10) {
            int gg = g0 + q / 10, j = q % 10;
            pack[(size_t)b * PACKF + 224 + gg * 10 + j] =
                targets[((size_t)b * G + gg) * 15 + 4 + j];
        }
    }
    __syncthreads();
    float4 tb0 = s_box[0], tb1 = s_box[1], tb2 = s_box[2], tb3 = s_box[3];
    float at0 = s_at[0], at1 = s_at[1], at2 = s_at[2], at3 = s_at[3];
    float c0 = 0.35f * at0, c1 = 0.35f * at1, c2 = 0.35f * at2, c3 = 0.35f * at3;

    u64* __restrict__ wm = wmask + ((size_t)b * NCH + cx) * NW64A;

    float bv[GPB]; int bp[GPB];
    #pragma unroll
    for (int j = 0; j < GPB; ++j) { bv[j] = -1.f; bp[j] = 0; }

    for (int p = tid; p < P; p += GNT) {     // ascending p: '>' keeps smallest p
        float4 pr = priors[p];
        float hx = pr.z * 0.5f, hy = pr.w * 0.5f;
        float px0 = pr.x - hx, py0 = pr.y - hy;
        float px1 = pr.x + hx, py1 = pr.y + hy;
        float ap = (px1 - px0) * (py1 - py0);
        float ap35 = 0.35f * ap;
        bool pa = false;
        #pragma unroll
        for (int j = 0; j < GPB; ++j) {
            float4 tb = j == 0 ? tb0 : (j == 1 ? tb1 : (j == 2 ? tb2 : tb3));
            float at = j == 0 ? at0 : (j == 1 ? at1 : (j == 2 ? at2 : at3));
            float cj = j == 0 ? c0 : (j == 1 ? c1 : (j == 2 ? c2 : c3));
            float lx = fmaxf(tb.x, px0), ly = fmaxf(tb.y, py0);
            float rx = fminf(tb.z, px1), ry = fminf(tb.w, py1);
            float iw = fmaxf(rx - lx, 0.f), ih = fmaxf(ry - ly, 0.f);
            float inter = iw * ih;
            // iou >= 0.35 <=> 1.35*inter - 0.35*at >= 0.35*ap  (same as r8-r12)
            pa = pa || (fmaf(1.35f, inter, -cj) >= ap35);
            float iou = inter * RCP(at + ap - inter);
            if (iou > bv[j]) { bv[j] = iou; bp[j] = p; }
        }
        u64 bal = __ballot(pa);                       // bit per prior in this word
        if (lane == 0) wm[p >> 6] = bal;
    }
    #pragma unroll
    for (int j = 0; j < GPB; ++j) {
        u64 key = ((u64)__float_as_uint(bv[j]) << 32) | ~(unsigned)bp[j];
        #pragma unroll
        for (int o = 32; o > 0; o >>= 1) {
            u64 t = __shfl_down(key, o, 64);
            if (t > key) key = t;
        }
        if (lane == 0) s_wk[w][j] = key;
    }
    __syncthreads();
    if (tid < GPB) {
        u64 m = 0ull;
        #pragma unroll
        for (int q = 0; q < GNT / 64; ++q) { u64 t = s_wk[q][tid]; if (t > m) m = t; }
        keys[b * G + g0 + tid] = m;
    }
}

// ---- k_match: no g-loop; threshold from wmask ----
__global__ __launch_bounds__(256)
void k_match(const float2* __restrict__ cls, const float4* __restrict__ loc,
             const float* __restrict__ lmd, const float4* __restrict__ priors,
             const float* __restrict__ pack, const u64* __restrict__ keys,
             const u64* __restrict__ wmask,
             float* __restrict__ bc, float* __restrict__ part,
             int P, int NB, int NCH) {
    const int b = blockIdx.y, bx = blockIdx.x, tid = threadIdx.x;
    const int lane = tid & 63, w = tid >> 6;
    const float* __restrict__ pk = pack + (size_t)b * PACKF;
    const float4* __restrict__ gbox = (const float4*)pk;
    const float* __restrict__ garea = pk + 160;
    const float* __restrict__ glab = pk + 192;
    const float* __restrict__ glm  = pk + 224;

    __shared__ int s_fg[256];
    __shared__ int s_fv[256];
    __shared__ unsigned s_vm;
    __shared__ float s_red[4][8];

    s_fg[tid] = -1; s_fv[tid] = 0;
    __syncthreads();
    if (tid < GN) {                                   // forced-match scatter
        u64 key = keys[b * GN + tid];
        unsigned bp = ~(unsigned)key;
        bool val = __uint_as_float((unsigned)(key >> 32)) >= 0.2f;
        u64 bal = __ballot(val);
        if (tid == 0) s_vm = (unsigned)bal;
        int local = (int)bp - bx * 256;
        if (local >= 0 && local < 256) {
            atomicMax(&s_fg[local], tid);
            if (val) atomicOr(&s_fv[local], 1);
        }
    }

    int p = bx * 256 + tid;
    const bool act = p < P;
    float2 c = act ? cls[(size_t)b * P + p] : make_float2(0.f, 0.f);

    // threshold: OR the 8 chunk masks for this wave's 64-prior word (uniform loads)
    const int word = bx * 4 + w;
    u64 m = 0ull;
    #pragma unroll
    for (int ch = 0; ch < 8; ++ch)
        m |= wmask[((size_t)b * NCH + ch) * NW64A + word];
    __syncthreads();                                  // covers scatter
    const bool av = s_vm != 0u;

    bool thr = act && ((m >> lane) & 1ull);
    int fidx = s_fg[tid];
    bool fv = s_fv[tid] != 0;
    bool pos = act && av && (fv || thr);

    float lse = 0.f, d = 0.f;
    if (act) {
        d = c.y - c.x;
        float m0 = fmaxf(d, 0.f);
        lse = m0 + __logf(__expf(-m0) + __expf(d - m0));   // logz - c.x >= 0
        bc[(size_t)b * P + p] = pos ? 0.f : lse;
    }

    float a_ll = 0.f, a_lm = 0.f, a_lcp = 0.f;
    bool posl = false;
    if (pos) {                                        // rare path only touches priors
        a_lcp = lse - d;
        float4 pr = priors[p];
        float hx = pr.z * 0.5f, hy = pr.w * 0.5f;
        float px0 = pr.x - hx, py0 = pr.y - hy;
        float px1 = pr.x + hx, py1 = pr.y + hy;
        float ap = (px1 - px0) * (py1 - py0);
        int bti2 = fidx;
        if (fidx < 0) {                               // full first-g argmax
            float btv = -1.f;
            #pragma unroll 1
            for (int g = 0; g < GN; ++g) {
                float4 tb = gbox[g];
                float lx = fmaxf(tb.x, px0), ly = fmaxf(tb.y, py0);
                float rx = fminf(tb.z, px1), ry = fminf(tb.w, py1);
                float iw = fmaxf(rx - lx, 0.f), ih = fmaxf(ry - ly, 0.f);
                float inter = iw * ih;
                float iou = inter * RCP(garea[g] + ap - inter);
                if (iou > btv) { btv = iou; bti2 = g; }
            }
        }
        float4 tb = gbox[bti2];
        float rw = RCP(pr.z), rh = RCP(pr.w);
        float e0 = ((tb.x + tb.z) * 0.5f - pr.x) * rw * 10.f;
        float e1 = ((tb.y + tb.w) * 0.5f - pr.y) * rh * 10.f;
        float e2 = __logf((tb.z - tb.x) * rw) * 5.f;
        float e3 = __logf((tb.w - tb.y) * rh) * 5.f;
        float4 ld = loc[(size_t)b * P + p];
        a_ll = sl1(ld.x - e0) + sl1(ld.y - e1) + sl1(ld.z - e2) + sl1(ld.w - e3);
        if (glab[bti2] > 0.f) {
            posl = true;
            const float* lp = lmd + ((size_t)b * P + p) * 10;
            #pragma unroll
            for (int q = 0; q < 5; ++q) {
                float gx = (glm[bti2 * 10 + 2 * q]     - pr.x) * rw * 10.f;
                float gy = (glm[bti2 * 10 + 2 * q + 1] - pr.y) * rh * 10.f;
                a_lm += sl1(lp[2 * q] - gx) + sl1(lp[2 * q + 1] - gy);
            }
        }
    }

    u64 bpos = __ballot(pos);
    int npw  = __popcll(bpos);
    int np1w = __popcll(__ballot(posl));
    if (bpos) {                                       // skip shuffles for all-neg waves
        #pragma unroll
        for (int o = 32; o > 0; o >>= 1) {
            a_ll  += __shfl_down(a_ll,  o, 64);
            a_lm  += __shfl_down(a_lm,  o, 64);
            a_lcp += __shfl_down(a_lcp, o, 64);
        }
    }
    if (lane == 0) {
        s_red[w][0] = a_ll; s_red[w][1] = a_lm; s_red[w][2] = a_lcp;
        s_red[w][3] = (float)npw; s_red[w][4] = (float)np1w;
    }
    __syncthreads();
    if (tid == 0) {
        float* pp = part + ((size_t)b * NB + bx) * 8;
        #pragma unroll
        for (int j = 0; j < 5; ++j)
            pp[j] = s_red[0][j] + s_red[1][j] + s_red[2][j] + s_red[3][j];
    }
}

// ---- k_select: exact top-k via 4-way bisection; last block folds ----
constexpr int KNT = 1024;
constexpr int KNI = 17;      // ceil(16800 / 1024)
__global__ __launch_bounds__(KNT)
void k_select(const float* __restrict__ bc, const float* __restrict__ part,
              float* __restrict__ part2, float* __restrict__ out,
              int* __restrict__ done, int P, int NB, int B) {
    const int b = blockIdx.x, tid = threadIdx.x;
    const int lane = tid & 63, w = tid >> 6;
    __shared__ float s_r[5];
    __shared__ u64   s_cw[16];
    __shared__ u64   s_ct;
    __shared__ float s_rf[16][2];
    __shared__ float s_ts2[2];
    __shared__ int   s_last;

    unsigned ul[KNI];
    #pragma unroll
    for (int i = 0; i < KNI; ++i) {
        int idx = i * KNT + tid;
        ul[i] = idx < P ? __float_as_uint(bc[(size_t)b * P + idx]) : 0u;
    }
    if (w < 5) {                                      // wave j reduces part field j
        float s = 0.f;
        for (int bx = lane; bx < NB; bx += 64) s += part[((size_t)b * NB + bx) * 8 + w];
        #pragma unroll
        for (int o = 32; o > 0; o >>= 1) s += __shfl_down(s, o, 64);
        if (lane == 0) s_r[w] = s;
    }
    __syncthreads();
    const float t_ll = s_r[0], t_lm = s_r[1], t_lcp = s_r[2];
    const float t_np = s_r[3], t_np1 = s_r[4];
    int k = (int)(t_np + 0.5f) * 7;
    if (k > P - 1) k = P - 1;

    float topk = 0.f;
    if (k > 0) {
        unsigned lo = 0u, hi = 0x7f800000u;           // finite non-negative values
        while (lo < hi) {                             // ~15 rounds (4-way)
            unsigned span = hi - lo;
            unsigned m1 = lo + ((span + 3) >> 2);
            unsigned m2 = lo + ((span + 1) >> 1);
            unsigned m3 = hi - (span >> 2);
            int c1 = 0, c2 = 0, c3 = 0;
            #pragma unroll
            for (int i = 0; i < KNI; ++i) {
                unsigned u = ul[i];
                c1 += u >= m1 ? 1 : 0;
                c2 += u >= m2 ? 1 : 0;
                c3 += u >= m3 ? 1 : 0;
            }
            u64 pkk = (u64)c1 | ((u64)c2 << 20) | ((u64)c3 << 40);
            #pragma unroll
            for (int o = 32; o > 0; o >>= 1) pkk += __shfl_down(pkk, o, 64);
            if (lane == 0) s_cw[w] = pkk;
            __syncthreads();
            if (w == 0) {
                u64 t = (lane < 16) ? s_cw[lane] : 0ull;
                #pragma unroll
                for (int o = 8; o > 0; o >>= 1) t += __shfl_down(t, o, 64);
                if (lane == 0) s_ct = t;
            }
            __syncthreads();
            u64 t = s_ct;
            int C1 = (int)(t & 0xFFFFFu);
            int C2 = (int)((t >> 20) & 0xFFFFFu);
            int C3 = (int)((t >> 40) & 0xFFFFFu);
            if      (C3 >= k) lo = m3;
            else if (C2 >= k) { lo = m2; hi = m3 - 1; }
            else if (C1 >= k) { lo = m1; hi = m2 - 1; }
            else hi = m1 - 1;
        }
        float fT = __uint_as_float(lo);               // exact k-th largest
        float s = 0.f, cf = 0.f;
        #pragma unroll
        for (int i = 0; i < KNI; ++i)
            if (ul[i] > lo) { s += __uint_as_float(ul[i]); cf += 1.f; }
        #pragma unroll
        for (int o = 32; o > 0; o >>= 1) {
            s  += __shfl_down(s, o, 64);
            cf += __shfl_down(cf, o, 64);
        }
        if (lane == 0) { s_rf[w][0] = s; s_rf[w][1] = cf; }
        __syncthreads();
        if (w == 0) {
            float a = (lane < 16) ? s_rf[lane][0] : 0.f;
            float bb = (lane < 16) ? s_rf[lane][1] : 0.f;
            #pragma unroll
            for (int o = 8; o > 0; o >>= 1) {
                a  += __shfl_down(a, o, 64);
                bb += __shfl_down(bb, o, 64);
            }
            if (lane == 0) { s_ts2[0] = a; s_ts2[1] = bb; }
        }
        __syncthreads();
        topk = s_ts2[0] + ((float)k - s_ts2[1]) * fT; // ties add (k-cnt)*T
    }
    if (tid == 0) {
        float* pp = part2 + b * 8;
        pp[0] = t_ll; pp[1] = t_lm; pp[2] = t_lcp;
        pp[3] = topk; pp[4] = t_np; pp[5] = t_np1;
        __threadfence();
        int old = atomicAdd(done, 1);
        s_last = (old == B - 1) ? 1 : 0;
    }
    __syncthreads();
    if (s_last && w == 0) {                           // last block folds all rows
        __threadfence();
        volatile float* vp = part2;
        float ll = 0.f, lm = 0.f, lc = 0.f, tk = 0.f, np = 0.f, np1 = 0.f;
        for (int bb = lane; bb < B; bb += 64) {
            ll  += vp[bb * 8 + 0];
            lm  += vp[bb * 8 + 1];
            lc  += vp[bb * 8 + 2];
            tk  += vp[bb * 8 + 3];
            np  += vp[bb * 8 + 4];
            np1 += vp[bb * 8 + 5];
        }
        #pragma unroll
        for (int o = 32; o > 0; o >>= 1) {
            ll  += __shfl_down(ll,  o, 64);
            lm  += __shfl_down(lm,  o, 64);
            lc  += __shfl_down(lc,  o, 64);
            tk  += __shfl_down(tk,  o, 64);
            np  += __shfl_down(np,  o, 64);
            np1 += __shfl_down(np1, o, 64);
        }
        if (lane == 0) {
            float N = fmaxf(np, 1.f), N1 = fmaxf(np1, 1.f);
            out[0] = ll / N;
            out[1] = (lc + tk) / N;
            out[2] = lm / N1;
        }
    }
}

extern "C" void kernel_launch(void* const* d_in, const int* in_sizes, int n_in,
                              void* d_out, int out_size, void* d_ws, size_t ws_size,
                              hipStream_t stream) {
    const float2* cls    = (const float2*)d_in[0];
    const float4* loc    = (const float4*)d_in[1];
    const float* lmd     = (const float*)d_in[2];
    const float4* priors = (const float4*)d_in[3];
    const float* targets = (const float*)d_in[4];
    int P = in_sizes[3] / 4;            // 16800
    int B = (in_sizes[1] / 4) / P;      // 64
    int G = in_sizes[4] / (15 * B);     // 32
    int NB = (P + 255) / 256;           // 66
    int NCH = (G + GPB - 1) / GPB;      // 8 chunks

    size_t off = 0;
    u64* keys    = (u64*)d_ws;                     off += (size_t)B * G * 8;
    u64* wmask   = (u64*)((char*)d_ws + off);      off += (size_t)B * NCH * NW64A * 8;
    float* pack  = (float*)((char*)d_ws + off);    off += (size_t)B * PACKF * 4;
    float* part  = (float*)((char*)d_ws + off);    off += (size_t)B * NB * 8 * 4;
    float* part2 = (float*)((char*)d_ws + off);    off += (size_t)B * 8 * 4;
    int* done    = (int*)((char*)d_ws + off);      off += 256;
    off = (off + 255) & ~(size_t)255;
    float* bc    = (float*)((char*)d_ws + off);

    dim3 ggt(NCH, B);
    k_gt<<<ggt, GNT, 0, stream>>>(priors, targets, keys, pack, wmask, done, P, G, NCH);
    dim3 gm(NB, B);
    k_match<<<gm, 256, 0, stream>>>(cls, loc, lmd, priors, pack, keys, wmask,
                                    bc, part, P, NB, NCH);
    k_select<<<B, KNT, 0, stream>>>(bc, part, part2, (float*)d_out, done, P, NB, B);
}